// Round 11
// baseline (156.834 us; speedup 1.0000x reference)
//
#include <hip/hip_runtime.h>
#include <math.h>

#define T_SEQ   2048
#define DMODEL  512
#define NHEADS  8
#define DH      64
#define NEG_INF -1.0e9f

typedef __attribute__((ext_vector_type(8))) short short8;
typedef __attribute__((ext_vector_type(4))) float f32x4;
typedef unsigned int u32;
typedef unsigned short u16;

// cheap bf16 pack: round-half-up, error <= 2^-9 rel (same bound as RNE). No NaNs here.
__device__ __forceinline__ u16 f2bf(float f) {
    union { float f; u32 u; } w; w.f = f;
    return (u16)((w.u + 0x8000u) >> 16);
}

// packed f32x2 -> bf16x2 (RNE), single instruction on gfx950
__device__ __forceinline__ u32 cvt_pk_bf16(float lo, float hi) {
    u32 r;
    asm("v_cvt_pk_bf16_f32 %0, %1, %2" : "=v"(r) : "v"(lo), "v"(hi));
    return r;
}

// async global->LDS, 16B per lane. LDS dest must be wave-uniform base + lane*16.
__device__ __forceinline__ void async_load16(const u16* g, u16* l) {
    __builtin_amdgcn_global_load_lds(
        (const __attribute__((address_space(1))) u32*)(const void*)g,
        (__attribute__((address_space(3))) u32*)(void*)l, 16, 0, 0);
}

// ---------------------------------------------------------------------------
// fused fp32->bf16 casts (x + 4 weights) + span-loss scalar. 5120 blocks.
// ---------------------------------------------------------------------------
__global__ void cast_all(const float* __restrict__ x,  const float* __restrict__ wq,
                         const float* __restrict__ wk, const float* __restrict__ wv,
                         const float* __restrict__ wo, const float* __restrict__ sp,
                         u16* __restrict__ xb,  u16* __restrict__ wqb,
                         u16* __restrict__ wkb, u16* __restrict__ wvb,
                         u16* __restrict__ wob, float* __restrict__ loss_out)
{
    const int bid = blockIdx.x;
    const float* src; u16* dst; int i;
    if (bid < 4096) { src = x; dst = xb; i = bid * 256 + threadIdx.x; }
    else {
        const int wsel = (bid - 4096) >> 8;
        src = (wsel == 0) ? wq : (wsel == 1) ? wk : (wsel == 2) ? wv : wo;
        dst = (wsel == 0) ? wqb : (wsel == 1) ? wkb : (wsel == 2) ? wvb : wob;
        i = ((bid - 4096) & 255) * 256 + threadIdx.x;
    }
    float4 v = ((const float4*)src)[i];
    ushort4 o;
    o.x = f2bf(v.x); o.y = f2bf(v.y); o.z = f2bf(v.z); o.w = f2bf(v.w);
    ((ushort4*)dst)[i] = o;
    if (bid == 5119 && threadIdx.x == 0) {
        float s = 0.0f;
        for (int h = 0; h < NHEADS; ++h)
            s += fminf(fmaxf(sp[h], 0.0f), 1.0f);
        loss_out[0] = 2e-4f * (s * 0.125f);
    }
}

// ---------------------------------------------------------------------------
// bf16 MFMA GEMM: C[m][n] = sum_k A[m][k]*W[n][k]  (A @ W^T)
// scatter=1: bf16 -> (B,H,T,DH) via LDS-coalesced epilogue.
//   z==2 additionally writes TRANSPOSED (B,H,DH,T) -- fuses the V-transpose
//   into the projection GEMM (removes the separate transpose_v kernel and
//   the V (B,H,T,DH) round-trip through HBM).
// scatter=0: fp32 row-major.
// ---------------------------------------------------------------------------
__global__ __launch_bounds__(256)
void gemm_bf16(const u16* __restrict__ A,
               const u16* __restrict__ W0, const u16* __restrict__ W1,
               const u16* __restrict__ W2,
               u16* __restrict__ Cb0, u16* __restrict__ Cb1,
               u16* __restrict__ Cb2,
               float* __restrict__ Cf, int scatter)
{
    constexpr int K = 512, BK = 64;
    const u16* W  = (blockIdx.z == 0) ? W0 : (blockIdx.z == 1) ? W1 : W2;
    u16*       Cb = (blockIdx.z == 0) ? Cb0 : (blockIdx.z == 1) ? Cb1 : Cb2;

    __shared__ __align__(16) u16 smem[16384];   // 32 KB: As|Bs, reused by epilogue
    u16* As = smem;
    u16* Bs = smem + 8192;

    const int t    = threadIdx.x;
    const int lane = t & 63;
    const int wave = t >> 6;
    const int wm   = wave >> 1, wn = wave & 1;
    const int m0   = blockIdx.x * 128, n0 = blockIdx.y * 128;

    const int srow = t >> 3;
    const int kb   = (t & 7) ^ (srow & 7);
    const u16* gA = A + (size_t)(m0 + srow) * K + kb * 8;
    const u16* gW = W + (size_t)(n0 + srow) * K + kb * 8;

    const int rA = wm * 64 + (lane & 15);
    const int rB = wn * 64 + (lane & 15);
    const int kq = lane >> 4;
    const int offA0 = rA * BK + ((kq      ^ (rA & 7)) * 8);
    const int offA1 = rA * BK + (((4 + kq) ^ (rA & 7)) * 8);
    const int offB0 = rB * BK + ((kq      ^ (rB & 7)) * 8);
    const int offB1 = rB * BK + (((4 + kq) ^ (rB & 7)) * 8);

    f32x4 acc[4][4];
#pragma unroll
    for (int it = 0; it < 4; ++it)
#pragma unroll
        for (int jt = 0; jt < 4; ++jt) acc[it][jt] = (f32x4)0.0f;

    for (int k0 = 0; k0 < K; k0 += BK) {
        __syncthreads();
#pragma unroll
        for (int i = 0; i < 4; ++i) {
            async_load16(gA + k0 + i * (32 * K), As + t * 8 + i * 2048);
            async_load16(gW + k0 + i * (32 * K), Bs + t * 8 + i * 2048);
        }
        __syncthreads();

        short8 af[4][2], bfr[4][2];
#pragma unroll
        for (int it = 0; it < 4; ++it) {
            af[it][0]  = *(const short8*)(As + offA0 + it * 16 * BK);
            af[it][1]  = *(const short8*)(As + offA1 + it * 16 * BK);
            bfr[it][0] = *(const short8*)(Bs + offB0 + it * 16 * BK);
            bfr[it][1] = *(const short8*)(Bs + offB1 + it * 16 * BK);
        }
#pragma unroll
        for (int it = 0; it < 4; ++it)
#pragma unroll
            for (int jt = 0; jt < 4; ++jt) {
                acc[it][jt] = __builtin_amdgcn_mfma_f32_16x16x32_bf16(
                    af[it][0], bfr[jt][0], acc[it][jt], 0, 0, 0);
                acc[it][jt] = __builtin_amdgcn_mfma_f32_16x16x32_bf16(
                    af[it][1], bfr[jt][1], acc[it][jt], 0, 0, 0);
            }
    }

    const int r0 = (lane >> 4) * 4;
    const int cl = lane & 15;

    if (scatter) {
        // two rounds; each stages a 64-row x 128-col bf16 slice (pitch 136) in LDS.
        constexpr int P = 136;
        const bool vt = (blockIdx.z == 2);   // V: drain transposed to (B,H,DH,T)
#pragma unroll
        for (int rnd = 0; rnd < 2; ++rnd) {
            __syncthreads();   // prior use of smem done
#pragma unroll
            for (int s = 0; s < 2; ++s) {
                const int it = rnd * 2 + s;
                const int lrow = wm * 32 + s * 16 + r0;
#pragma unroll
                for (int jt = 0; jt < 4; ++jt) {
                    const int cc = wn * 64 + jt * 16 + cl;
#pragma unroll
                    for (int r = 0; r < 4; ++r)
                        smem[(lrow + r) * P + cc] = f2bf(acc[it][jt][r]);
                }
            }
            __syncthreads();
            if (!vt) {
                // coalesced (B,H,T,DH) drain
                const int lrow2 = t >> 2;
                const int h2    = (t >> 1) & 1;
                const int dhalf = t & 1;
                const int grow  = m0 + (lrow2 >> 5) * 64 + rnd * 32 + (lrow2 & 31);
                const int b     = grow >> 11, tt = grow & 2047;
                const int h     = (n0 >> 6) + h2;
                u16* dst = Cb + ((size_t)((b * NHEADS + h) * T_SEQ + tt)) * DH + dhalf * 32;
                const u16* srcl = smem + lrow2 * P + h2 * 64 + dhalf * 32;
#pragma unroll
                for (int i = 0; i < 4; ++i)
                    ((uint4*)dst)[i] = *(const uint4*)(srcl + i * 8);
            } else {
                // transposed (B,H,DH,T) drain: 1024 tasks = 128 cols x 8 row-octets.
                // lanes sharing a column use rotation (j+oct)&7 so the 8 rows hit
                // 8 distinct banks (row*68 % 32 == 4*((j+oct)&7)).
#pragma unroll
                for (int it2 = 0; it2 < 4; ++it2) {
                    const int task = it2 * 256 + t;
                    const int oct  = task & 7;
                    const int col  = task >> 3;                  // 0..127
                    const int L    = (oct & 3) * 8 + (oct >> 2) * 32;
                    const int grow0 = m0 + (oct >> 2) * 64 + rnd * 32 + (oct & 3) * 8;
                    const int bb = grow0 >> 11, tt = grow0 & 2047;
                    const int hh = (n0 >> 6) + (col >> 6);
                    const int dd = col & 63;
                    union { uint4 v; u16 s[8]; } pk;
#pragma unroll
                    for (int j = 0; j < 8; ++j) {
                        const int r = (j + oct) & 7;
                        pk.s[r] = smem[(L + r) * P + col];
                    }
                    *(uint4*)(Cb + ((size_t)((bb * NHEADS + hh) * DH + dd)) * T_SEQ + tt) = pk.v;
                }
            }
        }
    } else {
#pragma unroll
        for (int it = 0; it < 4; ++it) {
#pragma unroll
            for (int r = 0; r < 4; ++r) {
                const int row = m0 + wm * 64 + it * 16 + r0 + r;
#pragma unroll
                for (int jt = 0; jt < 4; ++jt) {
                    const int col = n0 + wn * 64 + jt * 16 + cl;
                    Cf[(size_t)row * DMODEL + col] = acc[it][jt][r];
                }
            }
        }
    }
}

// ---------------------------------------------------------------------------
// MFMA windowed flash attention (round-8 structure, best measured: total
// 149.8us). Block = 2 waves x 16 q; single-buffer global_load_lds staging
// with __syncthreads (every pipelining variant -- LDS dbuf r6, counted-vmcnt
// r1, reg-prefetch r9/r10 -- measured WORSE: cross-block TLP at 8 blocks/CU
// dominates intra-block pipelining for this kernel).
// Mapping: l = h*256 + b*64 + qb', qb rotated by head -> each stride-256
// resident class spans all 8 heads AND a stride-8 qb spread -> per-CU work
// uniform. Swapped-operand MFMA softmax: lane owns q-row, scalar m/l state.
// Q,K in (B,H,T,DH); Vt in (B,H,DH,T); out bf16 (B,T,DMODEL).
// ---------------------------------------------------------------------------
__global__ __launch_bounds__(128)
void attn_mfma(const u16* __restrict__ Q, const u16* __restrict__ K,
               const u16* __restrict__ Vt, const float* __restrict__ span_params,
               u16* __restrict__ out)
{
    __shared__ __align__(16) u16 Ks[64 * 64];      // [j][dh], XOR-swizzled granules
    __shared__ __align__(16) u16 Vs[64 * 64];      // [dh][j], XOR-swizzled granules
    __shared__ __align__(16) u16 Ps[2][1024];      // per-wave P [q=16][j=64], row 128B

    const int tid  = threadIdx.x;
    const int lane = tid & 63;
    const int w    = tid >> 6;
    const int nl   = lane & 15;
    const int quad = lane >> 4;
    const int swz  = (nl & 7) << 3;                // u16-unit XOR (bytes: (nl&7)<<4)

    // balanced bijective mapping: head from high bits, qb rotated by head so
    // each stride-256 resident class spans all heads AND a stride-8 qb spread.
    const int l  = blockIdx.x;              // 0..2047
    const int kk = l >> 8;                  // 0..7
    const int c  = l & 255;
    const int h  = kk;
    const int b  = c >> 6;
    const int qb = ((c & 63) + 8 * kk) & 63;
    const int bh = b * 8 + h;
    const int i0 = qb * 32;
    const int q0 = i0 + w * 16;

    const u16* Qh = Q  + (size_t)bh * (T_SEQ * DH);
    const u16* Kh = K  + (size_t)bh * (T_SEQ * DH);
    const u16* Vh = Vt + (size_t)bh * (DH * T_SEQ);

    float span = span_params[h];
    span = fminf(fmaxf(span, 0.0f), 1.0f);
    const float eff_span = span * 512.0f;
    const int wspan = (int)(eff_span + 1.0f) + 1;

    const float SCL = 0.125f * 1.44269504f;  // (1/sqrt(64)) * log2(e)

    // Q fragments (used as MFMA B-operand; same per-lane layout as A)
    short8 qf0 = *(const short8*)(Qh + (size_t)(q0 + nl) * DH + quad * 8);
    short8 qf1 = *(const short8*)(Qh + (size_t)(q0 + nl) * DH + 32 + quad * 8);

    // staging: 128 threads, 16 rows per issue, 4 issues per buffer
    const int srow = tid >> 3;                     // 0..15
    const int sg   = (tid & 7) ^ (srow & 7);
    const u16* gK = Kh + (size_t)srow * DH + sg * 8;
    const u16* gV = Vh + (size_t)srow * T_SEQ + sg * 8;

    f32x4 o[4];                 // O[q=nl][dcol = d*16 + quad*4 + r]
    float m_r = -1.0e30f, l_r = 0.0f;
#pragma unroll
    for (int d = 0; d < 4; ++d) o[d] = (f32x4)0.0f;

    int j_lo = i0 - wspan;
    if (j_lo < 0) j_lo = 0;
    j_lo &= ~63;

    u16* Psw = Ps[w];

    for (int j0 = j_lo; j0 <= i0 + 31; j0 += 64) {
        __syncthreads();
#pragma unroll
        for (int i = 0; i < 4; ++i) {
            async_load16(gK + (size_t)(j0 + i * 16) * DH, Ks + tid * 8 + i * 1024);
            async_load16(gV + j0 + (size_t)(i * 16) * T_SEQ, Vs + tid * 8 + i * 1024);
        }
        __syncthreads();

        // ---- S^T = K Q^T per 16-wide key tile: lane holds S[q=nl][j=quad*4+r]
        f32x4 s[4];
        bool any[4];
        __builtin_amdgcn_s_setprio(1);
#pragma unroll
        for (int n = 0; n < 4; ++n) {
            const int jn = j0 + n * 16;
            any[n] = (jn <= q0 + 15) &&
                     ((float)(q0 - jn - 15) < eff_span + 1.0f);   // R>0 exists
            s[n] = (f32x4)0.0f;
            if (any[n]) {
                const int row = n * 16 + nl;
                const u16* kp = Ks + row * 64;
                short8 b0 = *(const short8*)(kp + ((quad ^ (row & 7)) * 8));
                short8 b1 = *(const short8*)(kp + (((4 + quad) ^ (row & 7)) * 8));
                s[n] = __builtin_amdgcn_mfma_f32_16x16x32_bf16(b0, qf0, s[n], 0, 0, 0);
                s[n] = __builtin_amdgcn_mfma_f32_16x16x32_bf16(b1, qf1, s[n], 0, 0, 0);
            }
        }
        __builtin_amdgcn_s_setprio(0);

        // ---- mask + row max (per-lane scalar), 3-way tile classification ----
        const int qg = q0 + nl;
        float tmax = -1.0e30f;
#pragma unroll
        for (int n = 0; n < 4; ++n) {
            if (!any[n]) continue;
            const int jn = j0 + n * 16;
            const int jb = jn + quad * 4;
            const bool causal_b = (jn + 15 > q0);                           // some dist<0
            const bool span_b   = ((float)(q0 + 15 - jn) > eff_span - 3.0f); // some R<1
            if (!causal_b && !span_b) {
#pragma unroll
                for (int r = 0; r < 4; ++r) {
                    const float sv = s[n][r] * SCL;
                    s[n][r] = sv;
                    tmax = fmaxf(tmax, sv);
                }
            } else if (!span_b) {
#pragma unroll
                for (int r = 0; r < 4; ++r) {
                    const int dist = qg - (jb + r);
                    const float sv = (dist >= 0) ? s[n][r] * SCL : NEG_INF;
                    s[n][r] = sv;
                    tmax = fmaxf(tmax, sv);
                }
            } else {
#pragma unroll
                for (int r = 0; r < 4; ++r) {
                    const int dist = qg - (jb + r);
                    float sv = NEG_INF;
                    if (dist >= 0) {
                        float xv = eff_span - (float)dist;
                        float R  = fminf(fmaxf((xv + 1.0f) * 0.25f, 0.0f), 1.0f);
                        if (R > 0.0f)
                            sv = s[n][r] * SCL +
                                 ((R < 1.0f) ? __log2f(R + 1e-10f) : 0.0f);
                    }
                    s[n][r] = sv;
                    tmax = fmaxf(tmax, sv);
                }
            }
        }

        // ---- online softmax state: scalar per lane (q = nl), 2 shuffles ----
        float t2 = fmaxf(tmax, __shfl_xor(tmax, 16));
        t2 = fmaxf(t2, __shfl_xor(t2, 32));
        const float m_new = fmaxf(m_r, t2);
        const float alpha = exp2f(m_r - m_new);
        m_r = m_new;

        // ---- P = exp2(S - m) -> bf16 Ps via cvt_pk + ds_write_b64 ----
        float psum = 0.0f;
#pragma unroll
        for (int n = 0; n < 4; ++n) {
            u32 w0 = 0, w1 = 0;
            if (any[n]) {
                const float p0 = exp2f(s[n][0] - m_r);
                const float p1 = exp2f(s[n][1] - m_r);
                const float p2 = exp2f(s[n][2] - m_r);
                const float p3 = exp2f(s[n][3] - m_r);
                psum += (p0 + p1) + (p2 + p3);
                w0 = cvt_pk_bf16(p0, p1);
                w1 = cvt_pk_bf16(p2, p3);
            }
            uint2 wv; wv.x = w0; wv.y = w1;
            *(uint2*)&Psw[nl * 64 + ((n * 16 + quad * 4) ^ swz)] = wv;
        }
        float ps = psum + __shfl_xor(psum, 16);
        ps += __shfl_xor(ps, 32);
        l_r = l_r * alpha + ps;
#pragma unroll
        for (int d = 0; d < 4; ++d)
#pragma unroll
            for (int r = 0; r < 4; ++r) o[d][r] *= alpha;

        // ---- O += V^T P^T (swapped): A = V-frag (unchanged reads), B = P-frag
        const bool kf0 = any[0] | any[1];
        const bool kf1 = any[2] | any[3];
        short8 pa0 = *(const short8*)&Psw[nl * 64 + ((quad * 8) ^ swz)];
        short8 pa1 = *(const short8*)&Psw[nl * 64 + ((32 + quad * 8) ^ swz)];
        __builtin_amdgcn_s_setprio(1);
#pragma unroll
        for (int d = 0; d < 4; ++d) {
            const int vrow = d * 16 + nl;
            const u16* vp = Vs + vrow * 64;
            if (kf0) {
                short8 vb0 = *(const short8*)(vp + ((quad ^ (vrow & 7)) * 8));
                o[d] = __builtin_amdgcn_mfma_f32_16x16x32_bf16(vb0, pa0, o[d], 0, 0, 0);
            }
            if (kf1) {
                short8 vb1 = *(const short8*)(vp + (((4 + quad) ^ (vrow & 7)) * 8));
                o[d] = __builtin_amdgcn_mfma_f32_16x16x32_bf16(vb1, pa1, o[d], 0, 0, 0);
            }
        }
        __builtin_amdgcn_s_setprio(0);
    }

    // ---- epilogue: O[q=nl][dcol=d*16+quad*4+r]; scalar 1/l; 8B stores ----
    const float inv_l = 1.0f / l_r;
    u16* op = out + (size_t)(b * T_SEQ + q0 + nl) * DMODEL + h * 64 + quad * 4;
#pragma unroll
    for (int d = 0; d < 4; ++d) {
        uint2 wv;
        wv.x = cvt_pk_bf16(o[d][0] * inv_l, o[d][1] * inv_l);
        wv.y = cvt_pk_bf16(o[d][2] * inv_l, o[d][3] * inv_l);
        *(uint2*)(op + d * 16) = wv;
    }
}

extern "C" void kernel_launch(void* const* d_in, const int* in_sizes, int n_in,
                              void* d_out, int out_size, void* d_ws, size_t ws_size,
                              hipStream_t stream)
{
    (void)in_sizes; (void)n_in; (void)out_size; (void)ws_size;
    const float* x  = (const float*)d_in[0];
    const float* wq = (const float*)d_in[1];
    const float* wk = (const float*)d_in[2];
    const float* wv = (const float*)d_in[3];
    const float* wo = (const float*)d_in[4];
    const float* sp = (const float*)d_in[5];
    float* out = (float*)d_out;

    const size_t elems = (size_t)4 * T_SEQ * DMODEL;  // 4,194,304
    u16* xb  = (u16*)d_ws;
    u16* Qb  = xb  + elems;
    u16* Kb  = Qb  + elems;
    u16* Vb  = Kb  + elems;    // unused (V written transposed directly)
    u16* Vtb = Vb  + elems;
    u16* Ab  = Vtb + elems;
    u16* wqb = Ab  + elems;
    u16* wkb = wqb + 262144;
    u16* wvb = wkb + 262144;
    u16* wob = wvb + 262144;

    // casts + loss (one launch)
    cast_all<<<5120, 256, 0, stream>>>(x, wq, wk, wv, wo, sp,
                                       xb, wqb, wkb, wvb, wob, out + elems);
    // Q,K,V projections; V drains transposed straight into Vtb (z==2)
    gemm_bf16<<<dim3(64, 4, 3), 256, 0, stream>>>(
        xb, wqb, wkb, wvb, Qb, Kb, Vtb, nullptr, 1);
    // LDS-staged MFMA windowed flash attention (round-8 structure)
    attn_mfma<<<dim3(2048), 128, 0, stream>>>(Qb, Kb, Vtb, sp, Ab);
    // output projection (fp32 out)
    gemm_bf16<<<dim3(64, 4, 1), 256, 0, stream>>>(
        Ab, wob, wob, wob, nullptr, nullptr, nullptr, out, 0);
}

// Round 12
// 152.299 us; speedup vs baseline: 1.0298x; 1.0298x over previous
//
#include <hip/hip_runtime.h>
#include <math.h>

#define T_SEQ   2048
#define DMODEL  512
#define NHEADS  8
#define DH      64
#define NEG_INF -1.0e9f

typedef __attribute__((ext_vector_type(8))) short short8;
typedef __attribute__((ext_vector_type(4))) float f32x4;
typedef unsigned int u32;
typedef unsigned short u16;

// cheap bf16 pack: round-half-up, error <= 2^-9 rel (same bound as RNE). No NaNs here.
__device__ __forceinline__ u16 f2bf(float f) {
    union { float f; u32 u; } w; w.f = f;
    return (u16)((w.u + 0x8000u) >> 16);
}

// packed f32x2 -> bf16x2 (RNE), single instruction on gfx950
__device__ __forceinline__ u32 cvt_pk_bf16(float lo, float hi) {
    u32 r;
    asm("v_cvt_pk_bf16_f32 %0, %1, %2" : "=v"(r) : "v"(lo), "v"(hi));
    return r;
}

// async global->LDS, 16B per lane. LDS dest must be wave-uniform base + lane*16.
__device__ __forceinline__ void async_load16(const u16* g, u16* l) {
    __builtin_amdgcn_global_load_lds(
        (const __attribute__((address_space(1))) u32*)(const void*)g,
        (__attribute__((address_space(3))) u32*)(void*)l, 16, 0, 0);
}

// raw barrier: no compiler-inserted vmcnt(0) drain. sched_barrier + "memory"
// clobber pin memory-op ordering; named SSA values are unaffected.
__device__ __forceinline__ void barrier_raw() {
    __builtin_amdgcn_sched_barrier(0);
    asm volatile("s_barrier" ::: "memory");
    __builtin_amdgcn_sched_barrier(0);
}

// ---------------------------------------------------------------------------
// fused fp32->bf16 casts (x + 4 weights) + span-loss scalar. 5120 blocks.
// ---------------------------------------------------------------------------
__global__ void cast_all(const float* __restrict__ x,  const float* __restrict__ wq,
                         const float* __restrict__ wk, const float* __restrict__ wv,
                         const float* __restrict__ wo, const float* __restrict__ sp,
                         u16* __restrict__ xb,  u16* __restrict__ wqb,
                         u16* __restrict__ wkb, u16* __restrict__ wvb,
                         u16* __restrict__ wob, float* __restrict__ loss_out)
{
    const int bid = blockIdx.x;
    const float* src; u16* dst; int i;
    if (bid < 4096) { src = x; dst = xb; i = bid * 256 + threadIdx.x; }
    else {
        const int wsel = (bid - 4096) >> 8;
        src = (wsel == 0) ? wq : (wsel == 1) ? wk : (wsel == 2) ? wv : wo;
        dst = (wsel == 0) ? wqb : (wsel == 1) ? wkb : (wsel == 2) ? wvb : wob;
        i = ((bid - 4096) & 255) * 256 + threadIdx.x;
    }
    float4 v = ((const float4*)src)[i];
    ushort4 o;
    o.x = f2bf(v.x); o.y = f2bf(v.y); o.z = f2bf(v.z); o.w = f2bf(v.w);
    ((ushort4*)dst)[i] = o;
    if (bid == 5119 && threadIdx.x == 0) {
        float s = 0.0f;
        for (int h = 0; h < NHEADS; ++h)
            s += fminf(fmaxf(sp[h], 0.0f), 1.0f);
        loss_out[0] = 2e-4f * (s * 0.125f);
    }
}

// ---------------------------------------------------------------------------
// bf16 MFMA GEMM: C[m][n] = sum_k A[m][k]*W[n][k]  (A @ W^T)
// scatter=1: bf16 -> (B,H,T,DH) via LDS-coalesced epilogue; 0: fp32 row-major.
// (round-8 version: the fused transposed-V drain (r11) regressed ~7us --
//  its 64B-segment stores at 4KB stride beat the cost of transpose_v.)
// ---------------------------------------------------------------------------
__global__ __launch_bounds__(256)
void gemm_bf16(const u16* __restrict__ A,
               const u16* __restrict__ W0, const u16* __restrict__ W1,
               const u16* __restrict__ W2,
               u16* __restrict__ Cb0, u16* __restrict__ Cb1,
               u16* __restrict__ Cb2,
               float* __restrict__ Cf, int scatter)
{
    constexpr int K = 512, BK = 64;
    const u16* W  = (blockIdx.z == 0) ? W0 : (blockIdx.z == 1) ? W1 : W2;
    u16*       Cb = (blockIdx.z == 0) ? Cb0 : (blockIdx.z == 1) ? Cb1 : Cb2;

    __shared__ __align__(16) u16 smem[16384];   // 32 KB: As|Bs, reused by epilogue
    u16* As = smem;
    u16* Bs = smem + 8192;

    const int t    = threadIdx.x;
    const int lane = t & 63;
    const int wave = t >> 6;
    const int wm   = wave >> 1, wn = wave & 1;
    const int m0   = blockIdx.x * 128, n0 = blockIdx.y * 128;

    const int srow = t >> 3;
    const int kb   = (t & 7) ^ (srow & 7);
    const u16* gA = A + (size_t)(m0 + srow) * K + kb * 8;
    const u16* gW = W + (size_t)(n0 + srow) * K + kb * 8;

    const int rA = wm * 64 + (lane & 15);
    const int rB = wn * 64 + (lane & 15);
    const int kq = lane >> 4;
    const int offA0 = rA * BK + ((kq      ^ (rA & 7)) * 8);
    const int offA1 = rA * BK + (((4 + kq) ^ (rA & 7)) * 8);
    const int offB0 = rB * BK + ((kq      ^ (rB & 7)) * 8);
    const int offB1 = rB * BK + (((4 + kq) ^ (rB & 7)) * 8);

    f32x4 acc[4][4];
#pragma unroll
    for (int it = 0; it < 4; ++it)
#pragma unroll
        for (int jt = 0; jt < 4; ++jt) acc[it][jt] = (f32x4)0.0f;

    for (int k0 = 0; k0 < K; k0 += BK) {
        __syncthreads();
#pragma unroll
        for (int i = 0; i < 4; ++i) {
            async_load16(gA + k0 + i * (32 * K), As + t * 8 + i * 2048);
            async_load16(gW + k0 + i * (32 * K), Bs + t * 8 + i * 2048);
        }
        __syncthreads();

        short8 af[4][2], bfr[4][2];
#pragma unroll
        for (int it = 0; it < 4; ++it) {
            af[it][0]  = *(const short8*)(As + offA0 + it * 16 * BK);
            af[it][1]  = *(const short8*)(As + offA1 + it * 16 * BK);
            bfr[it][0] = *(const short8*)(Bs + offB0 + it * 16 * BK);
            bfr[it][1] = *(const short8*)(Bs + offB1 + it * 16 * BK);
        }
#pragma unroll
        for (int it = 0; it < 4; ++it)
#pragma unroll
            for (int jt = 0; jt < 4; ++jt) {
                acc[it][jt] = __builtin_amdgcn_mfma_f32_16x16x32_bf16(
                    af[it][0], bfr[jt][0], acc[it][jt], 0, 0, 0);
                acc[it][jt] = __builtin_amdgcn_mfma_f32_16x16x32_bf16(
                    af[it][1], bfr[jt][1], acc[it][jt], 0, 0, 0);
            }
    }

    const int r0 = (lane >> 4) * 4;
    const int cl = lane & 15;

    if (scatter) {
        // two rounds; each stages a 64-row x 128-col bf16 slice (pitch 136) in LDS,
        // then stores coalesced uint4 to (B,H,T,DH).
        constexpr int P = 136;
#pragma unroll
        for (int rnd = 0; rnd < 2; ++rnd) {
            __syncthreads();   // prior use of smem done
#pragma unroll
            for (int s = 0; s < 2; ++s) {
                const int it = rnd * 2 + s;
                const int lrow = wm * 32 + s * 16 + r0;
#pragma unroll
                for (int jt = 0; jt < 4; ++jt) {
                    const int cc = wn * 64 + jt * 16 + cl;
#pragma unroll
                    for (int r = 0; r < 4; ++r)
                        smem[(lrow + r) * P + cc] = f2bf(acc[it][jt][r]);
                }
            }
            __syncthreads();
            const int lrow2 = t >> 2;
            const int h2    = (t >> 1) & 1;
            const int dhalf = t & 1;
            const int grow  = m0 + (lrow2 >> 5) * 64 + rnd * 32 + (lrow2 & 31);
            const int b     = grow >> 11, tt = grow & 2047;
            const int h     = (n0 >> 6) + h2;
            u16* dst = Cb + ((size_t)((b * NHEADS + h) * T_SEQ + tt)) * DH + dhalf * 32;
            const u16* srcl = smem + lrow2 * P + h2 * 64 + dhalf * 32;
#pragma unroll
            for (int i = 0; i < 4; ++i)
                ((uint4*)dst)[i] = *(const uint4*)(srcl + i * 8);
        }
    } else {
#pragma unroll
        for (int it = 0; it < 4; ++it) {
#pragma unroll
            for (int r = 0; r < 4; ++r) {
                const int row = m0 + wm * 64 + it * 16 + r0 + r;
#pragma unroll
                for (int jt = 0; jt < 4; ++jt) {
                    const int col = n0 + wn * 64 + jt * 16 + cl;
                    Cf[(size_t)row * DMODEL + col] = acc[it][jt][r];
                }
            }
        }
    }
}

// ---------------------------------------------------------------------------
// V (B,H,T,DH) -> Vt (B,H,DH,T), bf16, 64x64 LDS tiles.
// ---------------------------------------------------------------------------
__global__ __launch_bounds__(256)
void transpose_v(const u16* __restrict__ V, u16* __restrict__ Vt)
{
    __shared__ u16 tile[64][72];
    const int bh = blockIdx.y;
    const int j0 = blockIdx.x * 64;
    const u16* src = V + (size_t)bh * (T_SEQ * DH) + (size_t)j0 * DH;
    u16* dst = Vt + (size_t)bh * (T_SEQ * DH) + j0;
    const int t = threadIdx.x;
    const int jr = t >> 2, c0 = (t & 3) * 16;
    uint4 a = *(const uint4*)(src + (size_t)jr * DH + c0);
    uint4 b = *(const uint4*)(src + (size_t)jr * DH + c0 + 8);
    *(uint4*)&tile[jr][c0]     = a;
    *(uint4*)&tile[jr][c0 + 8] = b;
    __syncthreads();
    const int d = t >> 2, jc = (t & 3) * 16;
    union { uint4 v; u16 s[8]; } pa, pb;
#pragma unroll
    for (int i = 0; i < 8; ++i) pa.s[i] = tile[jc + i][d];
#pragma unroll
    for (int i = 0; i < 8; ++i) pb.s[i] = tile[jc + 8 + i][d];
    *(uint4*)(dst + (size_t)d * T_SEQ + jc)     = pa.v;
    *(uint4*)(dst + (size_t)d * T_SEQ + jc + 8) = pb.v;
}

// ---------------------------------------------------------------------------
// MFMA windowed flash attention v12 = round-8 + KVBLK=32 double-buffer.
// The untried cell of the pipeline/residency matrix: r6's dbuf@64 lost
// residency (37KB LDS -> 4 blk/CU); r8's single-buffer keeps 8 blk/CU but
// exposes a ~600-900cy vmcnt(0) drain per tile. dbuf@KVBLK=32 keeps LDS at
// EXACTLY 20480B (= r8) -> 8 blk/CU preserved, and counted vmcnt hides the
// drain: per tile {prefetch next 32-key slab (4 gload_lds) -> vmcnt(4)
// (tile-t done, prefetch in flight) -> raw barrier -> compute -> raw barrier}.
// Work per key unchanged (KVBLK=32 = one MFMA K-dim; PV = 1 MFMA/d).
// Mapping (h+qb interleave) and swapped-operand softmax unchanged.
// Q,K in (B,H,T,DH); Vt in (B,H,DH,T); out bf16 (B,T,DMODEL).
// ---------------------------------------------------------------------------
__global__ __launch_bounds__(128)
void attn_mfma(const u16* __restrict__ Q, const u16* __restrict__ K,
               const u16* __restrict__ Vt, const float* __restrict__ span_params,
               u16* __restrict__ out)
{
    __shared__ __align__(16) u16 Ks[2][32 * 64];   // [j][dh], XOR-swizzled granules
    __shared__ __align__(16) u16 Vs[2][64 * 32];   // [dh][j], XOR-swizzled granules
    __shared__ __align__(16) u16 Ps[2][16 * 64];   // per-wave P [q=16][j], pitch 64

    const int tid  = threadIdx.x;
    const int lane = tid & 63;
    const int w    = tid >> 6;
    const int nl   = lane & 15;
    const int quad = lane >> 4;
    const int swz  = (nl & 7) << 3;                // u16-unit XOR for Ps

    // balanced bijective mapping: head from high bits, qb rotated by head so
    // each stride-256 resident class spans all heads AND a stride-8 qb spread.
    const int l  = blockIdx.x;              // 0..2047
    const int kk = l >> 8;                  // 0..7
    const int c  = l & 255;
    const int h  = kk;
    const int b  = c >> 6;
    const int qb = ((c & 63) + 8 * kk) & 63;
    const int bh = b * 8 + h;
    const int i0 = qb * 32;
    const int q0 = i0 + w * 16;

    const u16* Qh = Q  + (size_t)bh * (T_SEQ * DH);
    const u16* Kh = K  + (size_t)bh * (T_SEQ * DH);
    const u16* Vh = Vt + (size_t)bh * (DH * T_SEQ);

    float span = span_params[h];
    span = fminf(fmaxf(span, 0.0f), 1.0f);
    const float eff_span = span * 512.0f;
    const int wspan = (int)(eff_span + 1.0f) + 1;

    const float SCL = 0.125f * 1.44269504f;  // (1/sqrt(64)) * log2(e)

    // Q fragments (used as MFMA B-operand; same per-lane layout as A)
    short8 qf0 = *(const short8*)(Qh + (size_t)(q0 + nl) * DH + quad * 8);
    short8 qf1 = *(const short8*)(Qh + (size_t)(q0 + nl) * DH + 32 + quad * 8);

    // K staging: 16 j-rows x 64 dh per issue, 2 issues per tile
    const int srowK = tid >> 3;                    // 0..15
    const int sgK   = (tid & 7) ^ (srowK & 7);
    const u16* gK = Kh + (size_t)srowK * DH + sgK * 8;
    // V staging: 32 dh-rows x 32 j per issue, 2 issues per tile
    const int srowV = tid >> 2;                    // 0..31
    const int sgV   = (tid & 3) ^ (srowV & 3);
    const u16* gV = Vh + (size_t)srowV * T_SEQ + sgV * 8;

#define STAGE_KV(bi, jj) do {                                                    \
        async_load16(gK + (size_t)(jj) * DH,              Ks[bi] + tid * 8);         \
        async_load16(gK + (size_t)((jj) + 16) * DH,       Ks[bi] + tid * 8 + 1024);  \
        async_load16(gV + (jj),                           Vs[bi] + tid * 8);         \
        async_load16(gV + (size_t)32 * T_SEQ + (jj),      Vs[bi] + tid * 8 + 1024);  \
    } while (0)

    f32x4 o[4];                 // O[q=nl][dcol = d*16 + quad*4 + r]
    float m_r = -1.0e30f, l_r = 0.0f;
#pragma unroll
    for (int d = 0; d < 4; ++d) o[d] = (f32x4)0.0f;

    int j_lo = i0 - wspan;
    if (j_lo < 0) j_lo = 0;
    j_lo &= ~31;
    const int nt = ((i0 + 31 - j_lo) >> 5) + 1;    // uniform across block

    u16* Psw = Ps[w];

    STAGE_KV(0, j_lo);                             // prologue: tile 0 -> buf 0
    int buf = 0;

    for (int t = 0; t < nt; ++t) {
        const int j0 = j_lo + (t << 5);

        if (t + 1 < nt) {
            STAGE_KV(buf ^ 1, j0 + 32);            // prefetch next slab
            asm volatile("s_waitcnt vmcnt(4)" ::: "memory");  // tile t done
        } else {
            asm volatile("s_waitcnt vmcnt(0)" ::: "memory");
        }
        barrier_raw();                             // tile-t data visible to all

        const u16* Kb = Ks[buf];
        const u16* Vb = Vs[buf];

        // ---- S^T = K Q^T per 16-wide key tile: lane holds S[q=nl][j=quad*4+r]
        f32x4 s[2];
        bool any[2];
        __builtin_amdgcn_s_setprio(1);
#pragma unroll
        for (int n = 0; n < 2; ++n) {
            const int jn = j0 + n * 16;
            any[n] = (jn <= q0 + 15) &&
                     ((float)(q0 - jn - 15) < eff_span + 1.0f);   // R>0 exists
            s[n] = (f32x4)0.0f;
            if (any[n]) {
                const int row = n * 16 + nl;
                const u16* kp = Kb + row * 64;
                short8 b0 = *(const short8*)(kp + ((quad ^ (row & 7)) * 8));
                short8 b1 = *(const short8*)(kp + (((4 + quad) ^ (row & 7)) * 8));
                s[n] = __builtin_amdgcn_mfma_f32_16x16x32_bf16(b0, qf0, s[n], 0, 0, 0);
                s[n] = __builtin_amdgcn_mfma_f32_16x16x32_bf16(b1, qf1, s[n], 0, 0, 0);
            }
        }
        __builtin_amdgcn_s_setprio(0);

        // ---- mask + row max (per-lane scalar), 3-way tile classification ----
        const int qg = q0 + nl;
        float tmax = -1.0e30f;
#pragma unroll
        for (int n = 0; n < 2; ++n) {
            if (!any[n]) continue;
            const int jn = j0 + n * 16;
            const int jb = jn + quad * 4;
            const bool causal_b = (jn + 15 > q0);                           // some dist<0
            const bool span_b   = ((float)(q0 + 15 - jn) > eff_span - 3.0f); // some R<1
            if (!causal_b && !span_b) {
#pragma unroll
                for (int r = 0; r < 4; ++r) {
                    const float sv = s[n][r] * SCL;
                    s[n][r] = sv;
                    tmax = fmaxf(tmax, sv);
                }
            } else if (!span_b) {
#pragma unroll
                for (int r = 0; r < 4; ++r) {
                    const int dist = qg - (jb + r);
                    const float sv = (dist >= 0) ? s[n][r] * SCL : NEG_INF;
                    s[n][r] = sv;
                    tmax = fmaxf(tmax, sv);
                }
            } else {
#pragma unroll
                for (int r = 0; r < 4; ++r) {
                    const int dist = qg - (jb + r);
                    float sv = NEG_INF;
                    if (dist >= 0) {
                        float xv = eff_span - (float)dist;
                        float R  = fminf(fmaxf((xv + 1.0f) * 0.25f, 0.0f), 1.0f);
                        if (R > 0.0f)
                            sv = s[n][r] * SCL +
                                 ((R < 1.0f) ? __log2f(R + 1e-10f) : 0.0f);
                    }
                    s[n][r] = sv;
                    tmax = fmaxf(tmax, sv);
                }
            }
        }

        // ---- online softmax state: scalar per lane (q = nl), 2 shuffles ----
        float t2 = fmaxf(tmax, __shfl_xor(tmax, 16));
        t2 = fmaxf(t2, __shfl_xor(t2, 32));
        const float m_new = fmaxf(m_r, t2);
        const float alpha = exp2f(m_r - m_new);
        m_r = m_new;

        // ---- P = exp2(S - m) -> bf16 Ps via cvt_pk + ds_write_b64 ----
        float psum = 0.0f;
#pragma unroll
        for (int n = 0; n < 2; ++n) {
            u32 w0 = 0, w1 = 0;
            if (any[n]) {
                const float p0 = exp2f(s[n][0] - m_r);
                const float p1 = exp2f(s[n][1] - m_r);
                const float p2 = exp2f(s[n][2] - m_r);
                const float p3 = exp2f(s[n][3] - m_r);
                psum += (p0 + p1) + (p2 + p3);
                w0 = cvt_pk_bf16(p0, p1);
                w1 = cvt_pk_bf16(p2, p3);
            }
            uint2 wv; wv.x = w0; wv.y = w1;
            *(uint2*)&Psw[nl * 64 + ((n * 16 + quad * 4) ^ swz)] = wv;
        }
        float ps = psum + __shfl_xor(psum, 16);
        ps += __shfl_xor(ps, 32);
        l_r = l_r * alpha + ps;
#pragma unroll
        for (int d = 0; d < 4; ++d)
#pragma unroll
            for (int r = 0; r < 4; ++r) o[d][r] *= alpha;

        // ---- O += V^T P^T (swapped): A = V-frag, B = P-frag; K=32 = 1 MFMA/d
        const bool kf = any[0] | any[1];
        short8 pa0 = *(const short8*)&Psw[nl * 64 + ((quad * 8) ^ swz)];
        __builtin_amdgcn_s_setprio(1);
        if (kf) {
#pragma unroll
            for (int d = 0; d < 4; ++d) {
                const int vrow = d * 16 + nl;
                const u16* vp = Vb + vrow * 32;
                short8 vb0 = *(const short8*)(vp + ((quad ^ (vrow & 3)) * 8));
                o[d] = __builtin_amdgcn_mfma_f32_16x16x32_bf16(vb0, pa0, o[d], 0, 0, 0);
            }
        }
        __builtin_amdgcn_s_setprio(0);

        barrier_raw();          // all waves done reading buf before overwrite
        buf ^= 1;
    }
#undef STAGE_KV

    // ---- epilogue: O[q=nl][dcol=d*16+quad*4+r]; scalar 1/l; 8B stores ----
    const float inv_l = 1.0f / l_r;
    u16* op = out + (size_t)(b * T_SEQ + q0 + nl) * DMODEL + h * 64 + quad * 4;
#pragma unroll
    for (int d = 0; d < 4; ++d) {
        uint2 wv;
        wv.x = cvt_pk_bf16(o[d][0] * inv_l, o[d][1] * inv_l);
        wv.y = cvt_pk_bf16(o[d][2] * inv_l, o[d][3] * inv_l);
        *(uint2*)(op + d * 16) = wv;
    }
}

extern "C" void kernel_launch(void* const* d_in, const int* in_sizes, int n_in,
                              void* d_out, int out_size, void* d_ws, size_t ws_size,
                              hipStream_t stream)
{
    (void)in_sizes; (void)n_in; (void)out_size; (void)ws_size;
    const float* x  = (const float*)d_in[0];
    const float* wq = (const float*)d_in[1];
    const float* wk = (const float*)d_in[2];
    const float* wv = (const float*)d_in[3];
    const float* wo = (const float*)d_in[4];
    const float* sp = (const float*)d_in[5];
    float* out = (float*)d_out;

    const size_t elems = (size_t)4 * T_SEQ * DMODEL;  // 4,194,304
    u16* xb  = (u16*)d_ws;
    u16* Qb  = xb  + elems;
    u16* Kb  = Qb  + elems;
    u16* Vb  = Kb  + elems;
    u16* Vtb = Vb  + elems;
    u16* Ab  = Vtb + elems;
    u16* wqb = Ab  + elems;
    u16* wkb = wqb + 262144;
    u16* wvb = wkb + 262144;
    u16* wob = wvb + 262144;

    // casts + loss (one launch)
    cast_all<<<5120, 256, 0, stream>>>(x, wq, wk, wv, wo, sp,
                                       xb, wqb, wkb, wvb, wob, out + elems);
    // Q,K,V projections
    gemm_bf16<<<dim3(64, 4, 3), 256, 0, stream>>>(
        xb, wqb, wkb, wvb, Qb, Kb, Vb, nullptr, 1);
    // V -> V^T per head
    transpose_v<<<dim3(32, 32), 256, 0, stream>>>(Vb, Vtb);
    // dbuf@KVBLK=32 MFMA windowed flash attention (20.5KB LDS, 8 blk/CU)
    attn_mfma<<<dim3(2048), 128, 0, stream>>>(Qb, Kb, Vtb, sp, Ab);
    // output projection (fp32 out)
    gemm_bf16<<<dim3(64, 4, 1), 256, 0, stream>>>(
        Ab, wob, wob, wob, nullptr, nullptr, nullptr, out, 0);
}

// Round 13
// 151.537 us; speedup vs baseline: 1.0350x; 1.0050x over previous
//
#include <hip/hip_runtime.h>
#include <math.h>

#define T_SEQ   2048
#define DMODEL  512
#define NHEADS  8
#define DH      64
#define NEG_INF -1.0e9f

typedef __attribute__((ext_vector_type(8))) short short8;
typedef __attribute__((ext_vector_type(4))) float f32x4;
typedef unsigned int u32;
typedef unsigned short u16;

// cheap bf16 pack: round-half-up, error <= 2^-9 rel (same bound as RNE). No NaNs here.
__device__ __forceinline__ u16 f2bf(float f) {
    union { float f; u32 u; } w; w.f = f;
    return (u16)((w.u + 0x8000u) >> 16);
}

// packed f32x2 -> bf16x2 (RNE), single instruction on gfx950
__device__ __forceinline__ u32 cvt_pk_bf16(float lo, float hi) {
    u32 r;
    asm("v_cvt_pk_bf16_f32 %0, %1, %2" : "=v"(r) : "v"(lo), "v"(hi));
    return r;
}

// async global->LDS, 16B per lane. LDS dest must be wave-uniform base + lane*16.
__device__ __forceinline__ void async_load16(const u16* g, u16* l) {
    __builtin_amdgcn_global_load_lds(
        (const __attribute__((address_space(1))) u32*)(const void*)g,
        (__attribute__((address_space(3))) u32*)(void*)l, 16, 0, 0);
}

// ---------------------------------------------------------------------------
// fused fp32->bf16 casts (x + 4 weights) + span-loss scalar. 2560 blocks,
// 2 float4 -> 1 uint4 (16B) store per thread (was 5120 blocks x 1 float4).
// ---------------------------------------------------------------------------
__global__ void cast_all(const float* __restrict__ x,  const float* __restrict__ wq,
                         const float* __restrict__ wk, const float* __restrict__ wv,
                         const float* __restrict__ wo, const float* __restrict__ sp,
                         u16* __restrict__ xb,  u16* __restrict__ wqb,
                         u16* __restrict__ wkb, u16* __restrict__ wvb,
                         u16* __restrict__ wob, float* __restrict__ loss_out)
{
    const int bid = blockIdx.x;
    const float* src; u16* dst; int g;
    if (bid < 2048) { src = x; dst = xb; g = bid * 256 + threadIdx.x; }
    else {
        const int wsel = (bid - 2048) >> 7;
        src = (wsel == 0) ? wq : (wsel == 1) ? wk : (wsel == 2) ? wv : wo;
        dst = (wsel == 0) ? wqb : (wsel == 1) ? wkb : (wsel == 2) ? wvb : wob;
        g = ((bid - 2048) & 127) * 256 + threadIdx.x;
    }
    float4 v0 = ((const float4*)src)[2 * g];
    float4 v1 = ((const float4*)src)[2 * g + 1];
    union { uint4 u; ushort4 h[2]; } o;
    o.h[0].x = f2bf(v0.x); o.h[0].y = f2bf(v0.y);
    o.h[0].z = f2bf(v0.z); o.h[0].w = f2bf(v0.w);
    o.h[1].x = f2bf(v1.x); o.h[1].y = f2bf(v1.y);
    o.h[1].z = f2bf(v1.z); o.h[1].w = f2bf(v1.w);
    ((uint4*)dst)[g] = o.u;
    if (bid == 2559 && threadIdx.x == 0) {
        float s = 0.0f;
        for (int h = 0; h < NHEADS; ++h)
            s += fminf(fmaxf(sp[h], 0.0f), 1.0f);
        loss_out[0] = 2e-4f * (s * 0.125f);
    }
}

// ---------------------------------------------------------------------------
// bf16 MFMA GEMM: C[m][n] = sum_k A[m][k]*W[n][k]  (A @ W^T)
// scatter=1: bf16 -> (B,H,T,DH) via LDS-coalesced epilogue; 0: fp32 row-major.
// (round-8 version: fused transposed-V drain (r11) regressed -- scattered
//  64B stores at 4KB stride cost more than the separate transpose_v kernel.)
// ---------------------------------------------------------------------------
__global__ __launch_bounds__(256)
void gemm_bf16(const u16* __restrict__ A,
               const u16* __restrict__ W0, const u16* __restrict__ W1,
               const u16* __restrict__ W2,
               u16* __restrict__ Cb0, u16* __restrict__ Cb1,
               u16* __restrict__ Cb2,
               float* __restrict__ Cf, int scatter)
{
    constexpr int K = 512, BK = 64;
    const u16* W  = (blockIdx.z == 0) ? W0 : (blockIdx.z == 1) ? W1 : W2;
    u16*       Cb = (blockIdx.z == 0) ? Cb0 : (blockIdx.z == 1) ? Cb1 : Cb2;

    __shared__ __align__(16) u16 smem[16384];   // 32 KB: As|Bs, reused by epilogue
    u16* As = smem;
    u16* Bs = smem + 8192;

    const int t    = threadIdx.x;
    const int lane = t & 63;
    const int wave = t >> 6;
    const int wm   = wave >> 1, wn = wave & 1;
    const int m0   = blockIdx.x * 128, n0 = blockIdx.y * 128;

    const int srow = t >> 3;
    const int kb   = (t & 7) ^ (srow & 7);
    const u16* gA = A + (size_t)(m0 + srow) * K + kb * 8;
    const u16* gW = W + (size_t)(n0 + srow) * K + kb * 8;

    const int rA = wm * 64 + (lane & 15);
    const int rB = wn * 64 + (lane & 15);
    const int kq = lane >> 4;
    const int offA0 = rA * BK + ((kq      ^ (rA & 7)) * 8);
    const int offA1 = rA * BK + (((4 + kq) ^ (rA & 7)) * 8);
    const int offB0 = rB * BK + ((kq      ^ (rB & 7)) * 8);
    const int offB1 = rB * BK + (((4 + kq) ^ (rB & 7)) * 8);

    f32x4 acc[4][4];
#pragma unroll
    for (int it = 0; it < 4; ++it)
#pragma unroll
        for (int jt = 0; jt < 4; ++jt) acc[it][jt] = (f32x4)0.0f;

    for (int k0 = 0; k0 < K; k0 += BK) {
        __syncthreads();
#pragma unroll
        for (int i = 0; i < 4; ++i) {
            async_load16(gA + k0 + i * (32 * K), As + t * 8 + i * 2048);
            async_load16(gW + k0 + i * (32 * K), Bs + t * 8 + i * 2048);
        }
        __syncthreads();

        short8 af[4][2], bfr[4][2];
#pragma unroll
        for (int it = 0; it < 4; ++it) {
            af[it][0]  = *(const short8*)(As + offA0 + it * 16 * BK);
            af[it][1]  = *(const short8*)(As + offA1 + it * 16 * BK);
            bfr[it][0] = *(const short8*)(Bs + offB0 + it * 16 * BK);
            bfr[it][1] = *(const short8*)(Bs + offB1 + it * 16 * BK);
        }
#pragma unroll
        for (int it = 0; it < 4; ++it)
#pragma unroll
            for (int jt = 0; jt < 4; ++jt) {
                acc[it][jt] = __builtin_amdgcn_mfma_f32_16x16x32_bf16(
                    af[it][0], bfr[jt][0], acc[it][jt], 0, 0, 0);
                acc[it][jt] = __builtin_amdgcn_mfma_f32_16x16x32_bf16(
                    af[it][1], bfr[jt][1], acc[it][jt], 0, 0, 0);
            }
    }

    const int r0 = (lane >> 4) * 4;
    const int cl = lane & 15;

    if (scatter) {
        // two rounds; each stages a 64-row x 128-col bf16 slice (pitch 136) in LDS,
        // then stores coalesced uint4 to (B,H,T,DH).
        constexpr int P = 136;
#pragma unroll
        for (int rnd = 0; rnd < 2; ++rnd) {
            __syncthreads();   // prior use of smem done
#pragma unroll
            for (int s = 0; s < 2; ++s) {
                const int it = rnd * 2 + s;
                const int lrow = wm * 32 + s * 16 + r0;
#pragma unroll
                for (int jt = 0; jt < 4; ++jt) {
                    const int cc = wn * 64 + jt * 16 + cl;
#pragma unroll
                    for (int r = 0; r < 4; ++r)
                        smem[(lrow + r) * P + cc] = f2bf(acc[it][jt][r]);
                }
            }
            __syncthreads();
            const int lrow2 = t >> 2;
            const int h2    = (t >> 1) & 1;
            const int dhalf = t & 1;
            const int grow  = m0 + (lrow2 >> 5) * 64 + rnd * 32 + (lrow2 & 31);
            const int b     = grow >> 11, tt = grow & 2047;
            const int h     = (n0 >> 6) + h2;
            u16* dst = Cb + ((size_t)((b * NHEADS + h) * T_SEQ + tt)) * DH + dhalf * 32;
            const u16* srcl = smem + lrow2 * P + h2 * 64 + dhalf * 32;
#pragma unroll
            for (int i = 0; i < 4; ++i)
                ((uint4*)dst)[i] = *(const uint4*)(srcl + i * 8);
        }
    } else {
#pragma unroll
        for (int it = 0; it < 4; ++it) {
#pragma unroll
            for (int r = 0; r < 4; ++r) {
                const int row = m0 + wm * 64 + it * 16 + r0 + r;
#pragma unroll
                for (int jt = 0; jt < 4; ++jt) {
                    const int col = n0 + wn * 64 + jt * 16 + cl;
                    Cf[(size_t)row * DMODEL + col] = acc[it][jt][r];
                }
            }
        }
    }
}

// ---------------------------------------------------------------------------
// V (B,H,T,DH) -> Vt (B,H,DH,T), bf16, 64x64 LDS tiles.
// ---------------------------------------------------------------------------
__global__ __launch_bounds__(256)
void transpose_v(const u16* __restrict__ V, u16* __restrict__ Vt)
{
    __shared__ u16 tile[64][72];
    const int bh = blockIdx.y;
    const int j0 = blockIdx.x * 64;
    const u16* src = V + (size_t)bh * (T_SEQ * DH) + (size_t)j0 * DH;
    u16* dst = Vt + (size_t)bh * (T_SEQ * DH) + j0;
    const int t = threadIdx.x;
    const int jr = t >> 2, c0 = (t & 3) * 16;
    uint4 a = *(const uint4*)(src + (size_t)jr * DH + c0);
    uint4 b = *(const uint4*)(src + (size_t)jr * DH + c0 + 8);
    *(uint4*)&tile[jr][c0]     = a;
    *(uint4*)&tile[jr][c0 + 8] = b;
    __syncthreads();
    const int d = t >> 2, jc = (t & 3) * 16;
    union { uint4 v; u16 s[8]; } pa, pb;
#pragma unroll
    for (int i = 0; i < 8; ++i) pa.s[i] = tile[jc + i][d];
#pragma unroll
    for (int i = 0; i < 8; ++i) pb.s[i] = tile[jc + 8 + i][d];
    *(uint4*)(dst + (size_t)d * T_SEQ + jc)     = pa.v;
    *(uint4*)(dst + (size_t)d * T_SEQ + jc + 8) = pb.v;
}

// ---------------------------------------------------------------------------
// MFMA windowed flash attention (round-8 structure -- best measured config,
// total 149.8us). Block = 2 waves x 16 q; single-buffer global_load_lds
// staging with __syncthreads. Structure-space fully explored and converged:
// dbuf@64 (r6), counted-vmcnt (r1), reg-prefetch (r9/r10), dbuf@32 (r12) all
// measured WORSE -- at 8 blocks/CU the cross-block TLP already hides most of
// the per-tile drain, and every pipelining scheme costs more (barriers,
// ds_writes, or residency) than the drain it removes.
// Mapping: l = h*256 + b*64 + qb', qb rotated by head -> each stride-256
// resident class spans all 8 heads AND a stride-8 qb spread -> per-CU work
// uniform. Swapped-operand MFMA softmax: lane owns q-row, scalar m/l state.
// Q,K in (B,H,T,DH); Vt in (B,H,DH,T); out bf16 (B,T,DMODEL).
// ---------------------------------------------------------------------------
__global__ __launch_bounds__(128)
void attn_mfma(const u16* __restrict__ Q, const u16* __restrict__ K,
               const u16* __restrict__ Vt, const float* __restrict__ span_params,
               u16* __restrict__ out)
{
    __shared__ __align__(16) u16 Ks[64 * 64];      // [j][dh], XOR-swizzled granules
    __shared__ __align__(16) u16 Vs[64 * 64];      // [dh][j], XOR-swizzled granules
    __shared__ __align__(16) u16 Ps[2][1024];      // per-wave P [q=16][j=64], row 128B

    const int tid  = threadIdx.x;
    const int lane = tid & 63;
    const int w    = tid >> 6;
    const int nl   = lane & 15;
    const int quad = lane >> 4;
    const int swz  = (nl & 7) << 3;                // u16-unit XOR (bytes: (nl&7)<<4)

    // balanced bijective mapping: head from high bits, qb rotated by head so
    // each stride-256 resident class spans all heads AND a stride-8 qb spread.
    const int l  = blockIdx.x;              // 0..2047
    const int kk = l >> 8;                  // 0..7
    const int c  = l & 255;
    const int h  = kk;
    const int b  = c >> 6;
    const int qb = ((c & 63) + 8 * kk) & 63;
    const int bh = b * 8 + h;
    const int i0 = qb * 32;
    const int q0 = i0 + w * 16;

    const u16* Qh = Q  + (size_t)bh * (T_SEQ * DH);
    const u16* Kh = K  + (size_t)bh * (T_SEQ * DH);
    const u16* Vh = Vt + (size_t)bh * (DH * T_SEQ);

    float span = span_params[h];
    span = fminf(fmaxf(span, 0.0f), 1.0f);
    const float eff_span = span * 512.0f;
    const int wspan = (int)(eff_span + 1.0f) + 1;

    const float SCL = 0.125f * 1.44269504f;  // (1/sqrt(64)) * log2(e)

    // Q fragments (used as MFMA B-operand; same per-lane layout as A)
    short8 qf0 = *(const short8*)(Qh + (size_t)(q0 + nl) * DH + quad * 8);
    short8 qf1 = *(const short8*)(Qh + (size_t)(q0 + nl) * DH + 32 + quad * 8);

    // staging: 128 threads, 16 rows per issue, 4 issues per buffer
    const int srow = tid >> 3;                     // 0..15
    const int sg   = (tid & 7) ^ (srow & 7);
    const u16* gK = Kh + (size_t)srow * DH + sg * 8;
    const u16* gV = Vh + (size_t)srow * T_SEQ + sg * 8;

    f32x4 o[4];                 // O[q=nl][dcol = d*16 + quad*4 + r]
    float m_r = -1.0e30f, l_r = 0.0f;
#pragma unroll
    for (int d = 0; d < 4; ++d) o[d] = (f32x4)0.0f;

    int j_lo = i0 - wspan;
    if (j_lo < 0) j_lo = 0;
    j_lo &= ~63;

    u16* Psw = Ps[w];

    for (int j0 = j_lo; j0 <= i0 + 31; j0 += 64) {
        __syncthreads();
#pragma unroll
        for (int i = 0; i < 4; ++i) {
            async_load16(gK + (size_t)(j0 + i * 16) * DH, Ks + tid * 8 + i * 1024);
            async_load16(gV + j0 + (size_t)(i * 16) * T_SEQ, Vs + tid * 8 + i * 1024);
        }
        __syncthreads();

        // ---- S^T = K Q^T per 16-wide key tile: lane holds S[q=nl][j=quad*4+r]
        f32x4 s[4];
        bool any[4];
        __builtin_amdgcn_s_setprio(1);
#pragma unroll
        for (int n = 0; n < 4; ++n) {
            const int jn = j0 + n * 16;
            any[n] = (jn <= q0 + 15) &&
                     ((float)(q0 - jn - 15) < eff_span + 1.0f);   // R>0 exists
            s[n] = (f32x4)0.0f;
            if (any[n]) {
                const int row = n * 16 + nl;
                const u16* kp = Ks + row * 64;
                short8 b0 = *(const short8*)(kp + ((quad ^ (row & 7)) * 8));
                short8 b1 = *(const short8*)(kp + (((4 + quad) ^ (row & 7)) * 8));
                s[n] = __builtin_amdgcn_mfma_f32_16x16x32_bf16(b0, qf0, s[n], 0, 0, 0);
                s[n] = __builtin_amdgcn_mfma_f32_16x16x32_bf16(b1, qf1, s[n], 0, 0, 0);
            }
        }
        __builtin_amdgcn_s_setprio(0);

        // ---- mask + row max (per-lane scalar), 3-way tile classification ----
        const int qg = q0 + nl;
        float tmax = -1.0e30f;
#pragma unroll
        for (int n = 0; n < 4; ++n) {
            if (!any[n]) continue;
            const int jn = j0 + n * 16;
            const int jb = jn + quad * 4;
            const bool causal_b = (jn + 15 > q0);                           // some dist<0
            const bool span_b   = ((float)(q0 + 15 - jn) > eff_span - 3.0f); // some R<1
            if (!causal_b && !span_b) {
#pragma unroll
                for (int r = 0; r < 4; ++r) {
                    const float sv = s[n][r] * SCL;
                    s[n][r] = sv;
                    tmax = fmaxf(tmax, sv);
                }
            } else if (!span_b) {
#pragma unroll
                for (int r = 0; r < 4; ++r) {
                    const int dist = qg - (jb + r);
                    const float sv = (dist >= 0) ? s[n][r] * SCL : NEG_INF;
                    s[n][r] = sv;
                    tmax = fmaxf(tmax, sv);
                }
            } else {
#pragma unroll
                for (int r = 0; r < 4; ++r) {
                    const int dist = qg - (jb + r);
                    float sv = NEG_INF;
                    if (dist >= 0) {
                        float xv = eff_span - (float)dist;
                        float R  = fminf(fmaxf((xv + 1.0f) * 0.25f, 0.0f), 1.0f);
                        if (R > 0.0f)
                            sv = s[n][r] * SCL +
                                 ((R < 1.0f) ? __log2f(R + 1e-10f) : 0.0f);
                    }
                    s[n][r] = sv;
                    tmax = fmaxf(tmax, sv);
                }
            }
        }

        // ---- online softmax state: scalar per lane (q = nl), 2 shuffles ----
        float t2 = fmaxf(tmax, __shfl_xor(tmax, 16));
        t2 = fmaxf(t2, __shfl_xor(t2, 32));
        const float m_new = fmaxf(m_r, t2);
        const float alpha = exp2f(m_r - m_new);
        m_r = m_new;

        // ---- P = exp2(S - m) -> bf16 Ps via cvt_pk + ds_write_b64 ----
        float psum = 0.0f;
#pragma unroll
        for (int n = 0; n < 4; ++n) {
            u32 w0 = 0, w1 = 0;
            if (any[n]) {
                const float p0 = exp2f(s[n][0] - m_r);
                const float p1 = exp2f(s[n][1] - m_r);
                const float p2 = exp2f(s[n][2] - m_r);
                const float p3 = exp2f(s[n][3] - m_r);
                psum += (p0 + p1) + (p2 + p3);
                w0 = cvt_pk_bf16(p0, p1);
                w1 = cvt_pk_bf16(p2, p3);
            }
            uint2 wv; wv.x = w0; wv.y = w1;
            *(uint2*)&Psw[nl * 64 + ((n * 16 + quad * 4) ^ swz)] = wv;
        }
        float ps = psum + __shfl_xor(psum, 16);
        ps += __shfl_xor(ps, 32);
        l_r = l_r * alpha + ps;
#pragma unroll
        for (int d = 0; d < 4; ++d)
#pragma unroll
            for (int r = 0; r < 4; ++r) o[d][r] *= alpha;

        // ---- O += V^T P^T (swapped): A = V-frag (unchanged reads), B = P-frag
        const bool kf0 = any[0] | any[1];
        const bool kf1 = any[2] | any[3];
        short8 pa0 = *(const short8*)&Psw[nl * 64 + ((quad * 8) ^ swz)];
        short8 pa1 = *(const short8*)&Psw[nl * 64 + ((32 + quad * 8) ^ swz)];
        __builtin_amdgcn_s_setprio(1);
#pragma unroll
        for (int d = 0; d < 4; ++d) {
            const int vrow = d * 16 + nl;
            const u16* vp = Vs + vrow * 64;
            if (kf0) {
                short8 vb0 = *(const short8*)(vp + ((quad ^ (vrow & 7)) * 8));
                o[d] = __builtin_amdgcn_mfma_f32_16x16x32_bf16(vb0, pa0, o[d], 0, 0, 0);
            }
            if (kf1) {
                short8 vb1 = *(const short8*)(vp + (((4 + quad) ^ (vrow & 7)) * 8));
                o[d] = __builtin_amdgcn_mfma_f32_16x16x32_bf16(vb1, pa1, o[d], 0, 0, 0);
            }
        }
        __builtin_amdgcn_s_setprio(0);
    }

    // ---- epilogue: O[q=nl][dcol=d*16+quad*4+r]; scalar 1/l; 8B stores ----
    const float inv_l = 1.0f / l_r;
    u16* op = out + (size_t)(b * T_SEQ + q0 + nl) * DMODEL + h * 64 + quad * 4;
#pragma unroll
    for (int d = 0; d < 4; ++d) {
        uint2 wv;
        wv.x = cvt_pk_bf16(o[d][0] * inv_l, o[d][1] * inv_l);
        wv.y = cvt_pk_bf16(o[d][2] * inv_l, o[d][3] * inv_l);
        *(uint2*)(op + d * 16) = wv;
    }
}

extern "C" void kernel_launch(void* const* d_in, const int* in_sizes, int n_in,
                              void* d_out, int out_size, void* d_ws, size_t ws_size,
                              hipStream_t stream)
{
    (void)in_sizes; (void)n_in; (void)out_size; (void)ws_size;
    const float* x  = (const float*)d_in[0];
    const float* wq = (const float*)d_in[1];
    const float* wk = (const float*)d_in[2];
    const float* wv = (const float*)d_in[3];
    const float* wo = (const float*)d_in[4];
    const float* sp = (const float*)d_in[5];
    float* out = (float*)d_out;

    const size_t elems = (size_t)4 * T_SEQ * DMODEL;  // 4,194,304
    u16* xb  = (u16*)d_ws;
    u16* Qb  = xb  + elems;
    u16* Kb  = Qb  + elems;
    u16* Vb  = Kb  + elems;
    u16* Vtb = Vb  + elems;
    u16* Ab  = Vtb + elems;
    u16* wqb = Ab  + elems;
    u16* wkb = wqb + 262144;
    u16* wvb = wkb + 262144;
    u16* wob = wvb + 262144;

    // casts + loss (one launch, 16B stores)
    cast_all<<<2560, 256, 0, stream>>>(x, wq, wk, wv, wo, sp,
                                       xb, wqb, wkb, wvb, wob, out + elems);
    // Q,K,V projections
    gemm_bf16<<<dim3(64, 4, 3), 256, 0, stream>>>(
        xb, wqb, wkb, wvb, Qb, Kb, Vb, nullptr, 1);
    // V -> V^T per head
    transpose_v<<<dim3(32, 32), 256, 0, stream>>>(Vb, Vtb);
    // LDS-staged MFMA windowed flash attention (round-8 structure)
    attn_mfma<<<dim3(2048), 128, 0, stream>>>(Qb, Kb, Vtb, sp, Ab);
    // output projection (fp32 out)
    gemm_bf16<<<dim3(64, 4, 1), 256, 0, stream>>>(
        Ab, wob, wob, wob, nullptr, nullptr, nullptr, out, 0);
}

// Round 14
// 151.165 us; speedup vs baseline: 1.0375x; 1.0025x over previous
//
#include <hip/hip_runtime.h>
#include <math.h>

#define T_SEQ   2048
#define DMODEL  512
#define NHEADS  8
#define DH      64
#define NEG_INF -1.0e9f

typedef __attribute__((ext_vector_type(8))) short short8;
typedef __attribute__((ext_vector_type(4))) float f32x4;
typedef unsigned int u32;
typedef unsigned short u16;

// cheap bf16 pack: round-half-up, error <= 2^-9 rel (same bound as RNE). No NaNs here.
__device__ __forceinline__ u16 f2bf(float f) {
    union { float f; u32 u; } w; w.f = f;
    return (u16)((w.u + 0x8000u) >> 16);
}

// packed f32x2 -> bf16x2 (RNE), single instruction on gfx950
__device__ __forceinline__ u32 cvt_pk_bf16(float lo, float hi) {
    u32 r;
    asm("v_cvt_pk_bf16_f32 %0, %1, %2" : "=v"(r) : "v"(lo), "v"(hi));
    return r;
}

// async global->LDS, 16B per lane. LDS dest must be wave-uniform base + lane*16.
__device__ __forceinline__ void async_load16(const u16* g, u16* l) {
    __builtin_amdgcn_global_load_lds(
        (const __attribute__((address_space(1))) u32*)(const void*)g,
        (__attribute__((address_space(3))) u32*)(void*)l, 16, 0, 0);
}

// ---------------------------------------------------------------------------
// fused fp32->bf16 casts (x + 4 weights) + span-loss scalar. 5120 blocks.
// ---------------------------------------------------------------------------
__global__ void cast_all(const float* __restrict__ x,  const float* __restrict__ wq,
                         const float* __restrict__ wk, const float* __restrict__ wv,
                         const float* __restrict__ wo, const float* __restrict__ sp,
                         u16* __restrict__ xb,  u16* __restrict__ wqb,
                         u16* __restrict__ wkb, u16* __restrict__ wvb,
                         u16* __restrict__ wob, float* __restrict__ loss_out)
{
    const int bid = blockIdx.x;
    const float* src; u16* dst; int i;
    if (bid < 4096) { src = x; dst = xb; i = bid * 256 + threadIdx.x; }
    else {
        const int wsel = (bid - 4096) >> 8;
        src = (wsel == 0) ? wq : (wsel == 1) ? wk : (wsel == 2) ? wv : wo;
        dst = (wsel == 0) ? wqb : (wsel == 1) ? wkb : (wsel == 2) ? wvb : wob;
        i = ((bid - 4096) & 255) * 256 + threadIdx.x;
    }
    float4 v = ((const float4*)src)[i];
    ushort4 o;
    o.x = f2bf(v.x); o.y = f2bf(v.y); o.z = f2bf(v.z); o.w = f2bf(v.w);
    ((ushort4*)dst)[i] = o;
    if (bid == 5119 && threadIdx.x == 0) {
        float s = 0.0f;
        for (int h = 0; h < NHEADS; ++h)
            s += fminf(fmaxf(sp[h], 0.0f), 1.0f);
        loss_out[0] = 2e-4f * (s * 0.125f);
    }
}

// ---------------------------------------------------------------------------
// bf16 MFMA GEMM: C[m][n] = sum_k A[m][k]*W[n][k]  (A @ W^T)
// scatter=1: bf16 -> (B,H,T,DH) via LDS-coalesced epilogue; 0: fp32 row-major.
// (fused transposed-V drain (r11) regressed -- scattered 64B stores at 4KB
//  stride cost more than the separate transpose_v kernel.)
// ---------------------------------------------------------------------------
__global__ __launch_bounds__(256)
void gemm_bf16(const u16* __restrict__ A,
               const u16* __restrict__ W0, const u16* __restrict__ W1,
               const u16* __restrict__ W2,
               u16* __restrict__ Cb0, u16* __restrict__ Cb1,
               u16* __restrict__ Cb2,
               float* __restrict__ Cf, int scatter)
{
    constexpr int K = 512, BK = 64;
    const u16* W  = (blockIdx.z == 0) ? W0 : (blockIdx.z == 1) ? W1 : W2;
    u16*       Cb = (blockIdx.z == 0) ? Cb0 : (blockIdx.z == 1) ? Cb1 : Cb2;

    __shared__ __align__(16) u16 smem[16384];   // 32 KB: As|Bs, reused by epilogue
    u16* As = smem;
    u16* Bs = smem + 8192;

    const int t    = threadIdx.x;
    const int lane = t & 63;
    const int wave = t >> 6;
    const int wm   = wave >> 1, wn = wave & 1;
    const int m0   = blockIdx.x * 128, n0 = blockIdx.y * 128;

    const int srow = t >> 3;
    const int kb   = (t & 7) ^ (srow & 7);
    const u16* gA = A + (size_t)(m0 + srow) * K + kb * 8;
    const u16* gW = W + (size_t)(n0 + srow) * K + kb * 8;

    const int rA = wm * 64 + (lane & 15);
    const int rB = wn * 64 + (lane & 15);
    const int kq = lane >> 4;
    const int offA0 = rA * BK + ((kq      ^ (rA & 7)) * 8);
    const int offA1 = rA * BK + (((4 + kq) ^ (rA & 7)) * 8);
    const int offB0 = rB * BK + ((kq      ^ (rB & 7)) * 8);
    const int offB1 = rB * BK + (((4 + kq) ^ (rB & 7)) * 8);

    f32x4 acc[4][4];
#pragma unroll
    for (int it = 0; it < 4; ++it)
#pragma unroll
        for (int jt = 0; jt < 4; ++jt) acc[it][jt] = (f32x4)0.0f;

    for (int k0 = 0; k0 < K; k0 += BK) {
        __syncthreads();
#pragma unroll
        for (int i = 0; i < 4; ++i) {
            async_load16(gA + k0 + i * (32 * K), As + t * 8 + i * 2048);
            async_load16(gW + k0 + i * (32 * K), Bs + t * 8 + i * 2048);
        }
        __syncthreads();

        short8 af[4][2], bfr[4][2];
#pragma unroll
        for (int it = 0; it < 4; ++it) {
            af[it][0]  = *(const short8*)(As + offA0 + it * 16 * BK);
            af[it][1]  = *(const short8*)(As + offA1 + it * 16 * BK);
            bfr[it][0] = *(const short8*)(Bs + offB0 + it * 16 * BK);
            bfr[it][1] = *(const short8*)(Bs + offB1 + it * 16 * BK);
        }
#pragma unroll
        for (int it = 0; it < 4; ++it)
#pragma unroll
            for (int jt = 0; jt < 4; ++jt) {
                acc[it][jt] = __builtin_amdgcn_mfma_f32_16x16x32_bf16(
                    af[it][0], bfr[jt][0], acc[it][jt], 0, 0, 0);
                acc[it][jt] = __builtin_amdgcn_mfma_f32_16x16x32_bf16(
                    af[it][1], bfr[jt][1], acc[it][jt], 0, 0, 0);
            }
    }

    const int r0 = (lane >> 4) * 4;
    const int cl = lane & 15;

    if (scatter) {
        // two rounds; each stages a 64-row x 128-col bf16 slice (pitch 136) in LDS,
        // then stores coalesced uint4 to (B,H,T,DH).
        constexpr int P = 136;
#pragma unroll
        for (int rnd = 0; rnd < 2; ++rnd) {
            __syncthreads();   // prior use of smem done
#pragma unroll
            for (int s = 0; s < 2; ++s) {
                const int it = rnd * 2 + s;
                const int lrow = wm * 32 + s * 16 + r0;
#pragma unroll
                for (int jt = 0; jt < 4; ++jt) {
                    const int cc = wn * 64 + jt * 16 + cl;
#pragma unroll
                    for (int r = 0; r < 4; ++r)
                        smem[(lrow + r) * P + cc] = f2bf(acc[it][jt][r]);
                }
            }
            __syncthreads();
            const int lrow2 = t >> 2;
            const int h2    = (t >> 1) & 1;
            const int dhalf = t & 1;
            const int grow  = m0 + (lrow2 >> 5) * 64 + rnd * 32 + (lrow2 & 31);
            const int b     = grow >> 11, tt = grow & 2047;
            const int h     = (n0 >> 6) + h2;
            u16* dst = Cb + ((size_t)((b * NHEADS + h) * T_SEQ + tt)) * DH + dhalf * 32;
            const u16* srcl = smem + lrow2 * P + h2 * 64 + dhalf * 32;
#pragma unroll
            for (int i = 0; i < 4; ++i)
                ((uint4*)dst)[i] = *(const uint4*)(srcl + i * 8);
        }
    } else {
#pragma unroll
        for (int it = 0; it < 4; ++it) {
#pragma unroll
            for (int r = 0; r < 4; ++r) {
                const int row = m0 + wm * 64 + it * 16 + r0 + r;
#pragma unroll
                for (int jt = 0; jt < 4; ++jt) {
                    const int col = n0 + wn * 64 + jt * 16 + cl;
                    Cf[(size_t)row * DMODEL + col] = acc[it][jt][r];
                }
            }
        }
    }
}

// ---------------------------------------------------------------------------
// V (B,H,T,DH) -> Vt (B,H,DH,T), bf16, 64x64 LDS tiles.
// ---------------------------------------------------------------------------
__global__ __launch_bounds__(256)
void transpose_v(const u16* __restrict__ V, u16* __restrict__ Vt)
{
    __shared__ u16 tile[64][72];
    const int bh = blockIdx.y;
    const int j0 = blockIdx.x * 64;
    const u16* src = V + (size_t)bh * (T_SEQ * DH) + (size_t)j0 * DH;
    u16* dst = Vt + (size_t)bh * (T_SEQ * DH) + j0;
    const int t = threadIdx.x;
    const int jr = t >> 2, c0 = (t & 3) * 16;
    uint4 a = *(const uint4*)(src + (size_t)jr * DH + c0);
    uint4 b = *(const uint4*)(src + (size_t)jr * DH + c0 + 8);
    *(uint4*)&tile[jr][c0]     = a;
    *(uint4*)&tile[jr][c0 + 8] = b;
    __syncthreads();
    const int d = t >> 2, jc = (t & 3) * 16;
    union { uint4 v; u16 s[8]; } pa, pb;
#pragma unroll
    for (int i = 0; i < 8; ++i) pa.s[i] = tile[jc + i][d];
#pragma unroll
    for (int i = 0; i < 8; ++i) pb.s[i] = tile[jc + 8 + i][d];
    *(uint4*)(dst + (size_t)d * T_SEQ + jc)     = pa.v;
    *(uint4*)(dst + (size_t)d * T_SEQ + jc + 8) = pb.v;
}

// ---------------------------------------------------------------------------
// MFMA windowed flash attention (champion config, measured 149.8us total).
// Block = 2 waves x 16 q; single-buffer global_load_lds staging with
// __syncthreads. Structure space fully explored and converged: dbuf@64 (r6),
// counted-vmcnt (r1), reg-prefetch (r9/r10), dbuf@32 (r12) all measured
// worse -- at 8 blocks/CU the cross-block TLP already hides most of the
// per-tile drain, and every pipelining scheme costs more (barriers,
// ds_writes, or residency) than the drain it removes. Wave count is capped
// at 16/CU by the 16-q/wave MFMA tiling; split-KV's merge traffic cancels
// its TLP gain.
// Mapping: l = h*256 + b*64 + qb', qb rotated by head -> each stride-256
// resident class spans all 8 heads AND a stride-8 qb spread -> per-CU work
// uniform. Swapped-operand MFMA softmax: lane owns q-row, scalar m/l state.
// Q,K in (B,H,T,DH); Vt in (B,H,DH,T); out bf16 (B,T,DMODEL).
// ---------------------------------------------------------------------------
__global__ __launch_bounds__(128)
void attn_mfma(const u16* __restrict__ Q, const u16* __restrict__ K,
               const u16* __restrict__ Vt, const float* __restrict__ span_params,
               u16* __restrict__ out)
{
    __shared__ __align__(16) u16 Ks[64 * 64];      // [j][dh], XOR-swizzled granules
    __shared__ __align__(16) u16 Vs[64 * 64];      // [dh][j], XOR-swizzled granules
    __shared__ __align__(16) u16 Ps[2][1024];      // per-wave P [q=16][j=64], row 128B

    const int tid  = threadIdx.x;
    const int lane = tid & 63;
    const int w    = tid >> 6;
    const int nl   = lane & 15;
    const int quad = lane >> 4;
    const int swz  = (nl & 7) << 3;                // u16-unit XOR (bytes: (nl&7)<<4)

    // balanced bijective mapping: head from high bits, qb rotated by head so
    // each stride-256 resident class spans all heads AND a stride-8 qb spread.
    const int l  = blockIdx.x;              // 0..2047
    const int kk = l >> 8;                  // 0..7
    const int c  = l & 255;
    const int h  = kk;
    const int b  = c >> 6;
    const int qb = ((c & 63) + 8 * kk) & 63;
    const int bh = b * 8 + h;
    const int i0 = qb * 32;
    const int q0 = i0 + w * 16;

    const u16* Qh = Q  + (size_t)bh * (T_SEQ * DH);
    const u16* Kh = K  + (size_t)bh * (T_SEQ * DH);
    const u16* Vh = Vt + (size_t)bh * (DH * T_SEQ);

    float span = span_params[h];
    span = fminf(fmaxf(span, 0.0f), 1.0f);
    const float eff_span = span * 512.0f;
    const int wspan = (int)(eff_span + 1.0f) + 1;

    const float SCL = 0.125f * 1.44269504f;  // (1/sqrt(64)) * log2(e)

    // Q fragments (used as MFMA B-operand; same per-lane layout as A)
    short8 qf0 = *(const short8*)(Qh + (size_t)(q0 + nl) * DH + quad * 8);
    short8 qf1 = *(const short8*)(Qh + (size_t)(q0 + nl) * DH + 32 + quad * 8);

    // staging: 128 threads, 16 rows per issue, 4 issues per buffer
    const int srow = tid >> 3;                     // 0..15
    const int sg   = (tid & 7) ^ (srow & 7);
    const u16* gK = Kh + (size_t)srow * DH + sg * 8;
    const u16* gV = Vh + (size_t)srow * T_SEQ + sg * 8;

    f32x4 o[4];                 // O[q=nl][dcol = d*16 + quad*4 + r]
    float m_r = -1.0e30f, l_r = 0.0f;
#pragma unroll
    for (int d = 0; d < 4; ++d) o[d] = (f32x4)0.0f;

    int j_lo = i0 - wspan;
    if (j_lo < 0) j_lo = 0;
    j_lo &= ~63;

    u16* Psw = Ps[w];

    for (int j0 = j_lo; j0 <= i0 + 31; j0 += 64) {
        __syncthreads();
#pragma unroll
        for (int i = 0; i < 4; ++i) {
            async_load16(gK + (size_t)(j0 + i * 16) * DH, Ks + tid * 8 + i * 1024);
            async_load16(gV + j0 + (size_t)(i * 16) * T_SEQ, Vs + tid * 8 + i * 1024);
        }
        __syncthreads();

        // ---- S^T = K Q^T per 16-wide key tile: lane holds S[q=nl][j=quad*4+r]
        f32x4 s[4];
        bool any[4];
        __builtin_amdgcn_s_setprio(1);
#pragma unroll
        for (int n = 0; n < 4; ++n) {
            const int jn = j0 + n * 16;
            any[n] = (jn <= q0 + 15) &&
                     ((float)(q0 - jn - 15) < eff_span + 1.0f);   // R>0 exists
            s[n] = (f32x4)0.0f;
            if (any[n]) {
                const int row = n * 16 + nl;
                const u16* kp = Ks + row * 64;
                short8 b0 = *(const short8*)(kp + ((quad ^ (row & 7)) * 8));
                short8 b1 = *(const short8*)(kp + (((4 + quad) ^ (row & 7)) * 8));
                s[n] = __builtin_amdgcn_mfma_f32_16x16x32_bf16(b0, qf0, s[n], 0, 0, 0);
                s[n] = __builtin_amdgcn_mfma_f32_16x16x32_bf16(b1, qf1, s[n], 0, 0, 0);
            }
        }
        __builtin_amdgcn_s_setprio(0);

        // ---- mask + row max (per-lane scalar), 3-way tile classification ----
        const int qg = q0 + nl;
        float tmax = -1.0e30f;
#pragma unroll
        for (int n = 0; n < 4; ++n) {
            if (!any[n]) continue;
            const int jn = j0 + n * 16;
            const int jb = jn + quad * 4;
            const bool causal_b = (jn + 15 > q0);                           // some dist<0
            const bool span_b   = ((float)(q0 + 15 - jn) > eff_span - 3.0f); // some R<1
            if (!causal_b && !span_b) {
#pragma unroll
                for (int r = 0; r < 4; ++r) {
                    const float sv = s[n][r] * SCL;
                    s[n][r] = sv;
                    tmax = fmaxf(tmax, sv);
                }
            } else if (!span_b) {
#pragma unroll
                for (int r = 0; r < 4; ++r) {
                    const int dist = qg - (jb + r);
                    const float sv = (dist >= 0) ? s[n][r] * SCL : NEG_INF;
                    s[n][r] = sv;
                    tmax = fmaxf(tmax, sv);
                }
            } else {
#pragma unroll
                for (int r = 0; r < 4; ++r) {
                    const int dist = qg - (jb + r);
                    float sv = NEG_INF;
                    if (dist >= 0) {
                        float xv = eff_span - (float)dist;
                        float R  = fminf(fmaxf((xv + 1.0f) * 0.25f, 0.0f), 1.0f);
                        if (R > 0.0f)
                            sv = s[n][r] * SCL +
                                 ((R < 1.0f) ? __log2f(R + 1e-10f) : 0.0f);
                    }
                    s[n][r] = sv;
                    tmax = fmaxf(tmax, sv);
                }
            }
        }

        // ---- online softmax state: scalar per lane (q = nl), 2 shuffles ----
        float t2 = fmaxf(tmax, __shfl_xor(tmax, 16));
        t2 = fmaxf(t2, __shfl_xor(t2, 32));
        const float m_new = fmaxf(m_r, t2);
        const float alpha = exp2f(m_r - m_new);
        m_r = m_new;

        // ---- P = exp2(S - m) -> bf16 Ps via cvt_pk + ds_write_b64 ----
        float psum = 0.0f;
#pragma unroll
        for (int n = 0; n < 4; ++n) {
            u32 w0 = 0, w1 = 0;
            if (any[n]) {
                const float p0 = exp2f(s[n][0] - m_r);
                const float p1 = exp2f(s[n][1] - m_r);
                const float p2 = exp2f(s[n][2] - m_r);
                const float p3 = exp2f(s[n][3] - m_r);
                psum += (p0 + p1) + (p2 + p3);
                w0 = cvt_pk_bf16(p0, p1);
                w1 = cvt_pk_bf16(p2, p3);
            }
            uint2 wv; wv.x = w0; wv.y = w1;
            *(uint2*)&Psw[nl * 64 + ((n * 16 + quad * 4) ^ swz)] = wv;
        }
        float ps = psum + __shfl_xor(psum, 16);
        ps += __shfl_xor(ps, 32);
        l_r = l_r * alpha + ps;
#pragma unroll
        for (int d = 0; d < 4; ++d)
#pragma unroll
            for (int r = 0; r < 4; ++r) o[d][r] *= alpha;

        // ---- O += V^T P^T (swapped): A = V-frag (unchanged reads), B = P-frag
        const bool kf0 = any[0] | any[1];
        const bool kf1 = any[2] | any[3];
        short8 pa0 = *(const short8*)&Psw[nl * 64 + ((quad * 8) ^ swz)];
        short8 pa1 = *(const short8*)&Psw[nl * 64 + ((32 + quad * 8) ^ swz)];
        __builtin_amdgcn_s_setprio(1);
#pragma unroll
        for (int d = 0; d < 4; ++d) {
            const int vrow = d * 16 + nl;
            const u16* vp = Vs + vrow * 64;
            if (kf0) {
                short8 vb0 = *(const short8*)(vp + ((quad ^ (vrow & 7)) * 8));
                o[d] = __builtin_amdgcn_mfma_f32_16x16x32_bf16(vb0, pa0, o[d], 0, 0, 0);
            }
            if (kf1) {
                short8 vb1 = *(const short8*)(vp + (((4 + quad) ^ (vrow & 7)) * 8));
                o[d] = __builtin_amdgcn_mfma_f32_16x16x32_bf16(vb1, pa1, o[d], 0, 0, 0);
            }
        }
        __builtin_amdgcn_s_setprio(0);
    }

    // ---- epilogue: O[q=nl][dcol=d*16+quad*4+r]; scalar 1/l; 8B stores ----
    const float inv_l = 1.0f / l_r;
    u16* op = out + (size_t)(b * T_SEQ + q0 + nl) * DMODEL + h * 64 + quad * 4;
#pragma unroll
    for (int d = 0; d < 4; ++d) {
        uint2 wv;
        wv.x = cvt_pk_bf16(o[d][0] * inv_l, o[d][1] * inv_l);
        wv.y = cvt_pk_bf16(o[d][2] * inv_l, o[d][3] * inv_l);
        *(uint2*)(op + d * 16) = wv;
    }
}

extern "C" void kernel_launch(void* const* d_in, const int* in_sizes, int n_in,
                              void* d_out, int out_size, void* d_ws, size_t ws_size,
                              hipStream_t stream)
{
    (void)in_sizes; (void)n_in; (void)out_size; (void)ws_size;
    const float* x  = (const float*)d_in[0];
    const float* wq = (const float*)d_in[1];
    const float* wk = (const float*)d_in[2];
    const float* wv = (const float*)d_in[3];
    const float* wo = (const float*)d_in[4];
    const float* sp = (const float*)d_in[5];
    float* out = (float*)d_out;

    const size_t elems = (size_t)4 * T_SEQ * DMODEL;  // 4,194,304
    u16* xb  = (u16*)d_ws;
    u16* Qb  = xb  + elems;
    u16* Kb  = Qb  + elems;
    u16* Vb  = Kb  + elems;
    u16* Vtb = Vb  + elems;
    u16* Ab  = Vtb + elems;
    u16* wqb = Ab  + elems;
    u16* wkb = wqb + 262144;
    u16* wvb = wkb + 262144;
    u16* wob = wvb + 262144;

    // casts + loss (one launch)
    cast_all<<<5120, 256, 0, stream>>>(x, wq, wk, wv, wo, sp,
                                       xb, wqb, wkb, wvb, wob, out + elems);
    // Q,K,V projections
    gemm_bf16<<<dim3(64, 4, 3), 256, 0, stream>>>(
        xb, wqb, wkb, wvb, Qb, Kb, Vb, nullptr, 1);
    // V -> V^T per head
    transpose_v<<<dim3(32, 32), 256, 0, stream>>>(Vb, Vtb);
    // LDS-staged MFMA windowed flash attention (champion structure)
    attn_mfma<<<dim3(2048), 128, 0, stream>>>(Qb, Kb, Vtb, sp, Ab);
    // output projection (fp32 out)
    gemm_bf16<<<dim3(64, 4, 1), 256, 0, stream>>>(
        Ab, wob, wob, wob, nullptr, nullptr, nullptr, out, 0);
}